// Round 1
// 1798.638 us; speedup vs baseline: 3.4666x; 3.4666x over previous
//
#include <hip/hip_runtime.h>
#include <hip/hip_bf16.h>

#define B 2
#define L 2048
#define D 1024
#define H 16
#define HD 64
#define LH 8
#define NEG_INF -1e30f

typedef __hip_bfloat16 bf16;

template<typename T> struct IsF32;
template<> struct IsF32<float> { static constexpr int value = 1; };
template<> struct IsF32<bf16>  { static constexpr int value = 0; };

__device__ __forceinline__ float ldf(const float* p, size_t i) { return p[i]; }
__device__ __forceinline__ float ldf(const bf16* p, size_t i) { return __bfloat162float(p[i]); }

// vectorized 4-element load -> float4 (bf16 is truncated fp32: shift-convert exact)
__device__ __forceinline__ float4 ld4(const float* p, size_t i) {
  return *reinterpret_cast<const float4*>(p + i);
}
__device__ __forceinline__ float4 ld4(const bf16* p, size_t i) {
  ushort4 u = *reinterpret_cast<const ushort4*>(p + i);
  float4 f;
  f.x = __uint_as_float(((unsigned)u.x) << 16);
  f.y = __uint_as_float(((unsigned)u.y) << 16);
  f.z = __uint_as_float(((unsigned)u.z) << 16);
  f.w = __uint_as_float(((unsigned)u.w) << 16);
  return f;
}
__device__ __forceinline__ unsigned short f2bf(float v) {
  bf16 h = __float2bfloat16(v);
  return *reinterpret_cast<unsigned short*>(&h);
}
__device__ __forceinline__ void st4(float* p, size_t i, float4 v) {
  *reinterpret_cast<float4*>(p + i) = v;
}
__device__ __forceinline__ void st4(bf16* p, size_t i, float4 v) {
  ushort4 u;
  u.x = f2bf(v.x); u.y = f2bf(v.y); u.z = f2bf(v.z); u.w = f2bf(v.w);
  *reinterpret_cast<ushort4*>(p + i) = u;
}

// Runtime dtype detection (unchanged): fp32 data reinterpreted as u16 pairs
// shows large "exponent" fields in low halves with prob ~1/3; bf16 N(0,1) never does.
__global__ void detect_dtype_kernel(const unsigned short* __restrict__ x,
                                    int* __restrict__ flag) {
  int bad = 0;
  for (int i = threadIdx.x; i < 1024; i += 64) {
    if (((x[i] >> 7) & 0xFF) >= 170) bad = 1;
  }
  unsigned long long m = __ballot(bad);
  if (threadIdx.x == 0) *flag = (m != 0ULL) ? 1 : 0;
}

// ---------------- Kernel 1: fused QKV projection (tiled fp32 GEMM) ----------------
// grid (M/64 = 64, 48), block 256. blockIdx.y: [0,16)=Q, [16,32)=K, [32,48)=V.
// BM=BN=64, BK=32, 4x4 micro-tile per thread. Writes fp32 Q/K/V in [B,H,L,HD].
template<typename T>
__global__ __launch_bounds__(256)
void proj_qkv_kernel(const int* __restrict__ flag,
                     const T* __restrict__ x,
                     const T* __restrict__ Wq, const T* __restrict__ bq,
                     const T* __restrict__ Wk, const T* __restrict__ bk,
                     const T* __restrict__ Wv, const T* __restrict__ bv,
                     float* __restrict__ Q, float* __restrict__ K,
                     float* __restrict__ V) {
  if (*flag != IsF32<T>::value) return;
  const int mat  = blockIdx.y >> 4;          // 0=Q 1=K 2=V
  const int col0 = (blockIdx.y & 15) * 64;
  const int row0 = blockIdx.x * 64;
  const T* W    = (mat == 0) ? Wq : (mat == 1) ? Wk : Wv;
  const T* bias = (mat == 0) ? bq : (mat == 1) ? bk : bv;
  float* out    = (mat == 0) ? Q  : (mat == 1) ? K  : V;

  __shared__ __align__(16) float As[32][68];   // As[kk][m] = x[row0+m][k0+kk] (transposed)
  __shared__ __align__(16) float Bs[32][68];   // Bs[kk][n] = W[k0+kk][col0+n]

  const int t = threadIdx.x;
  const int tx = t & 15, ty = t >> 4;
  float acc[4][4] = {};

  for (int k0 = 0; k0 < D; k0 += 32) {
    // stage x tile 64x32 (transpose on store)
    #pragma unroll
    for (int r = 0; r < 2; ++r) {
      const int m  = r * 32 + (t >> 3);
      const int kk = (t & 7) * 4;
      const float4 v = ld4(x, (size_t)(row0 + m) * D + k0 + kk);
      As[kk + 0][m] = v.x; As[kk + 1][m] = v.y; As[kk + 2][m] = v.z; As[kk + 3][m] = v.w;
    }
    // stage W tile 32x64 (natural)
    #pragma unroll
    for (int r = 0; r < 2; ++r) {
      const int kk = r * 16 + (t >> 4);
      const int n  = (t & 15) * 4;
      *reinterpret_cast<float4*>(&Bs[kk][n]) = ld4(W, (size_t)(k0 + kk) * D + col0 + n);
    }
    __syncthreads();
    #pragma unroll 8
    for (int kk = 0; kk < 32; ++kk) {
      const float4 a = *reinterpret_cast<const float4*>(&As[kk][ty * 4]);
      const float4 b = *reinterpret_cast<const float4*>(&Bs[kk][tx * 4]);
      const float av[4] = {a.x, a.y, a.z, a.w};
      const float bw[4] = {b.x, b.y, b.z, b.w};
      #pragma unroll
      for (int i = 0; i < 4; ++i)
        #pragma unroll
        for (int j = 0; j < 4; ++j)
          acc[i][j] = fmaf(av[i], bw[j], acc[i][j]);
    }
    __syncthreads();
  }

  // epilogue: bias + scatter into [B,H,L,HD]. col block is 64-wide => single head h.
  const int h = col0 >> 6;                    // head index
  float bj[4];
  #pragma unroll
  for (int j = 0; j < 4; ++j) bj[j] = ldf(bias, (size_t)(col0 + tx * 4 + j));
  #pragma unroll
  for (int i = 0; i < 4; ++i) {
    const int row = row0 + ty * 4 + i;
    const int bb = row >> 11;                 // / L
    const int l  = row & (L - 1);
    float4 o;
    o.x = acc[i][0] + bj[0]; o.y = acc[i][1] + bj[1];
    o.z = acc[i][2] + bj[2]; o.w = acc[i][3] + bj[3];
    *reinterpret_cast<float4*>(&out[((size_t)(bb * H + h) * L + l) * HD + tx * 4]) = o;
  }
}

// ---------------- Kernel 2: attention (flash-style 2-pass, fp32) ----------------
// grid (L/64, H, B), block 256. One block per (b, h, 64-row q-tile).
// Pass 1: running row max/sum over K tiles. Pass 2: recompute scores, normalize,
// write probs, accumulate PV with V tile in LDS. Causal heads skip masked tiles.
template<typename T>
__global__ __launch_bounds__(256)
void attn_kernel(const int* __restrict__ flag,
                 const float* __restrict__ Q, const float* __restrict__ K,
                 const float* __restrict__ V,
                 const T* __restrict__ lscale_p, const T* __restrict__ gscale_p,
                 T* __restrict__ attn_l, T* __restrict__ attn_g,
                 float* __restrict__ AO) {
  if (*flag != IsF32<T>::value) return;
  const int qt = blockIdx.x;
  const int h  = blockIdx.y;
  const int bb = blockIdx.z;
  const int t  = threadIdx.x;
  const int tx = t & 15, ty = t >> 4;
  const int q0 = qt * 64;

  const size_t bh = (size_t)bb * H + h;
  const float* Qbh = Q + bh * (size_t)L * HD;
  const float* Kbh = K + bh * (size_t)L * HD;
  const float* Vbh = V + bh * (size_t)L * HD;

  const bool is_local = (h < LH);
  const float cscale =
      (is_local ? ldf(lscale_p, (size_t)0) : ldf(gscale_p, (size_t)0)) * 0.125f;

  __shared__ __align__(16) float Qs[64][68];   // Qs[d][m] (transposed)
  __shared__ __align__(16) float Ks[64][68];   // Ks[d][k] (transposed)
  __shared__ __align__(16) float Vs[64][68];   // Vs[k][d] (natural)
  __shared__ __align__(16) float Ps[64][68];   // Ps[k][m] probs (transposed)

  // load Q tile (transpose on store); visible after first __syncthreads below
  #pragma unroll
  for (int r = 0; r < 4; ++r) {
    const int m  = r * 16 + (t >> 4);
    const int d0 = (t & 15) * 4;
    const float4 v = ld4(Qbh, (size_t)(q0 + m) * HD + d0);
    Qs[d0 + 0][m] = v.x; Qs[d0 + 1][m] = v.y; Qs[d0 + 2][m] = v.z; Qs[d0 + 3][m] = v.w;
  }

  float m_[4], l_[4];
  #pragma unroll
  for (int i = 0; i < 4; ++i) { m_[i] = NEG_INF; l_[i] = 0.f; }

  const int ktend = is_local ? (qt + 1) : (L / 64);   // causal heads: tiles beyond diag all masked

  // ---------------- pass 1: row max / sum ----------------
  for (int kt = 0; kt < ktend; ++kt) {
    #pragma unroll
    for (int r = 0; r < 4; ++r) {
      const int kk = r * 16 + (t >> 4);
      const int d0 = (t & 15) * 4;
      const float4 v = ld4(Kbh, (size_t)(kt * 64 + kk) * HD + d0);
      Ks[d0 + 0][kk] = v.x; Ks[d0 + 1][kk] = v.y; Ks[d0 + 2][kk] = v.z; Ks[d0 + 3][kk] = v.w;
    }
    __syncthreads();

    float s[4][4] = {};
    #pragma unroll 8
    for (int d = 0; d < 64; ++d) {
      const float4 a = *reinterpret_cast<const float4*>(&Qs[d][ty * 4]);
      const float4 b = *reinterpret_cast<const float4*>(&Ks[d][tx * 4]);
      const float av[4] = {a.x, a.y, a.z, a.w};
      const float bw[4] = {b.x, b.y, b.z, b.w};
      #pragma unroll
      for (int i = 0; i < 4; ++i)
        #pragma unroll
        for (int j = 0; j < 4; ++j)
          s[i][j] = fmaf(av[i], bw[j], s[i][j]);
    }
    const bool diag = is_local && (kt == qt);
    #pragma unroll
    for (int i = 0; i < 4; ++i) {
      #pragma unroll
      for (int j = 0; j < 4; ++j) {
        float v = s[i][j] * cscale;
        if (diag && (tx * 4 + j > ty * 4 + i)) v = NEG_INF;
        s[i][j] = v;
      }
    }
    // per-row (16-lane group) online max/sum update
    #pragma unroll
    for (int i = 0; i < 4; ++i) {
      float tm = fmaxf(fmaxf(s[i][0], s[i][1]), fmaxf(s[i][2], s[i][3]));
      tm = fmaxf(tm, __shfl_xor(tm, 1, 64));
      tm = fmaxf(tm, __shfl_xor(tm, 2, 64));
      tm = fmaxf(tm, __shfl_xor(tm, 4, 64));
      tm = fmaxf(tm, __shfl_xor(tm, 8, 64));
      const float mn = fmaxf(m_[i], tm);
      float sum = __expf(s[i][0] - mn) + __expf(s[i][1] - mn) +
                  __expf(s[i][2] - mn) + __expf(s[i][3] - mn);
      sum += __shfl_xor(sum, 1, 64);
      sum += __shfl_xor(sum, 2, 64);
      sum += __shfl_xor(sum, 4, 64);
      sum += __shfl_xor(sum, 8, 64);
      l_[i] = l_[i] * __expf(m_[i] - mn) + sum;   // exp(-inf)=0 on first tile
      m_[i] = mn;
    }
    __syncthreads();
  }

  float invl[4];
  #pragma unroll
  for (int i = 0; i < 4; ++i) invl[i] = 1.0f / l_[i];

  float o[4][4] = {};
  T* aout = is_local ? attn_l : attn_g;
  const size_t arow0 = ((size_t)(bb * LH + (is_local ? h : h - LH)) * L + q0) * L;

  // ---------------- pass 2: normalize + write probs + PV ----------------
  for (int kt = 0; kt < ktend; ++kt) {
    #pragma unroll
    for (int r = 0; r < 4; ++r) {
      const int kk = r * 16 + (t >> 4);
      const int d0 = (t & 15) * 4;
      const float4 v = ld4(Kbh, (size_t)(kt * 64 + kk) * HD + d0);
      Ks[d0 + 0][kk] = v.x; Ks[d0 + 1][kk] = v.y; Ks[d0 + 2][kk] = v.z; Ks[d0 + 3][kk] = v.w;
      *reinterpret_cast<float4*>(&Vs[kk][d0]) =
          ld4(Vbh, (size_t)(kt * 64 + kk) * HD + d0);
    }
    __syncthreads();

    float s[4][4] = {};
    #pragma unroll 8
    for (int d = 0; d < 64; ++d) {
      const float4 a = *reinterpret_cast<const float4*>(&Qs[d][ty * 4]);
      const float4 b = *reinterpret_cast<const float4*>(&Ks[d][tx * 4]);
      const float av[4] = {a.x, a.y, a.z, a.w};
      const float bw[4] = {b.x, b.y, b.z, b.w};
      #pragma unroll
      for (int i = 0; i < 4; ++i)
        #pragma unroll
        for (int j = 0; j < 4; ++j)
          s[i][j] = fmaf(av[i], bw[j], s[i][j]);
    }
    const bool diag = is_local && (kt == qt);
    #pragma unroll
    for (int i = 0; i < 4; ++i) {
      float4 pv;
      float v0 = s[i][0] * cscale, v1 = s[i][1] * cscale;
      float v2 = s[i][2] * cscale, v3 = s[i][3] * cscale;
      if (diag) {
        if (tx * 4 + 0 > ty * 4 + i) v0 = NEG_INF;
        if (tx * 4 + 1 > ty * 4 + i) v1 = NEG_INF;
        if (tx * 4 + 2 > ty * 4 + i) v2 = NEG_INF;
        if (tx * 4 + 3 > ty * 4 + i) v3 = NEG_INF;
      }
      pv.x = __expf(v0 - m_[i]) * invl[i];
      pv.y = __expf(v1 - m_[i]) * invl[i];
      pv.z = __expf(v2 - m_[i]) * invl[i];
      pv.w = __expf(v3 - m_[i]) * invl[i];
      st4(aout, arow0 + (size_t)(ty * 4 + i) * L + kt * 64 + tx * 4, pv);
      Ps[tx * 4 + 0][ty * 4 + i] = pv.x;
      Ps[tx * 4 + 1][ty * 4 + i] = pv.y;
      Ps[tx * 4 + 2][ty * 4 + i] = pv.z;
      Ps[tx * 4 + 3][ty * 4 + i] = pv.w;
    }
    __syncthreads();

    #pragma unroll 8
    for (int k = 0; k < 64; ++k) {
      const float4 a = *reinterpret_cast<const float4*>(&Ps[k][ty * 4]);
      const float4 b = *reinterpret_cast<const float4*>(&Vs[k][tx * 4]);
      const float av[4] = {a.x, a.y, a.z, a.w};
      const float bw[4] = {b.x, b.y, b.z, b.w};
      #pragma unroll
      for (int i = 0; i < 4; ++i)
        #pragma unroll
        for (int j = 0; j < 4; ++j)
          o[i][j] = fmaf(av[i], bw[j], o[i][j]);
    }
    __syncthreads();
  }

  // fully-masked tiles of causal heads: probs are exactly 0
  if (is_local) {
    const float4 z = make_float4(0.f, 0.f, 0.f, 0.f);
    for (int kt = ktend; kt < L / 64; ++kt) {
      #pragma unroll
      for (int i = 0; i < 4; ++i)
        st4(aout, arow0 + (size_t)(ty * 4 + i) * L + kt * 64 + tx * 4, z);
    }
  }

  // AO in [B,L,D]
  #pragma unroll
  for (int i = 0; i < 4; ++i) {
    float4 ov;
    ov.x = o[i][0]; ov.y = o[i][1]; ov.z = o[i][2]; ov.w = o[i][3];
    *reinterpret_cast<float4*>(
        &AO[((size_t)bb * L + q0 + ty * 4 + i) * D + h * HD + tx * 4]) = ov;
  }
}

// ---------------- Kernel 3: output projection (tiled fp32 GEMM) ----------------
// grid (64, 16), block 256. Same tile structure as kernel 1; AO is fp32.
template<typename T>
__global__ __launch_bounds__(256)
void out_proj_kernel(const int* __restrict__ flag,
                     const float* __restrict__ AO,
                     const T* __restrict__ Wo, const T* __restrict__ bo,
                     T* __restrict__ out) {
  if (*flag != IsF32<T>::value) return;
  const int col0 = blockIdx.y * 64;
  const int row0 = blockIdx.x * 64;

  __shared__ __align__(16) float As[32][68];
  __shared__ __align__(16) float Bs[32][68];

  const int t = threadIdx.x;
  const int tx = t & 15, ty = t >> 4;
  float acc[4][4] = {};

  for (int k0 = 0; k0 < D; k0 += 32) {
    #pragma unroll
    for (int r = 0; r < 2; ++r) {
      const int m  = r * 32 + (t >> 3);
      const int kk = (t & 7) * 4;
      const float4 v = ld4(AO, (size_t)(row0 + m) * D + k0 + kk);
      As[kk + 0][m] = v.x; As[kk + 1][m] = v.y; As[kk + 2][m] = v.z; As[kk + 3][m] = v.w;
    }
    #pragma unroll
    for (int r = 0; r < 2; ++r) {
      const int kk = r * 16 + (t >> 4);
      const int n  = (t & 15) * 4;
      *reinterpret_cast<float4*>(&Bs[kk][n]) = ld4(Wo, (size_t)(k0 + kk) * D + col0 + n);
    }
    __syncthreads();
    #pragma unroll 8
    for (int kk = 0; kk < 32; ++kk) {
      const float4 a = *reinterpret_cast<const float4*>(&As[kk][ty * 4]);
      const float4 b = *reinterpret_cast<const float4*>(&Bs[kk][tx * 4]);
      const float av[4] = {a.x, a.y, a.z, a.w};
      const float bw[4] = {b.x, b.y, b.z, b.w};
      #pragma unroll
      for (int i = 0; i < 4; ++i)
        #pragma unroll
        for (int j = 0; j < 4; ++j)
          acc[i][j] = fmaf(av[i], bw[j], acc[i][j]);
    }
    __syncthreads();
  }

  float bj[4];
  #pragma unroll
  for (int j = 0; j < 4; ++j) bj[j] = ldf(bo, (size_t)(col0 + tx * 4 + j));
  #pragma unroll
  for (int i = 0; i < 4; ++i) {
    const int row = row0 + ty * 4 + i;
    float4 o;
    o.x = acc[i][0] + bj[0]; o.y = acc[i][1] + bj[1];
    o.z = acc[i][2] + bj[2]; o.w = acc[i][3] + bj[3];
    st4(out, (size_t)row * D + col0 + tx * 4, o);
  }
}

template<typename T>
static void launch_path(void* const* d_in, void* d_out, void* d_ws, hipStream_t stream) {
  const size_t NQKV = (size_t)B * H * L * HD;   // 4,194,304
  const int* flag = (const int*)d_ws;
  float* Q  = (float*)((char*)d_ws + 256);
  float* K  = Q + NQKV;
  float* V  = K + NQKV;
  float* AO = V + NQKV;

  const T* x  = (const T*)d_in[0];
  const T* Wq = (const T*)d_in[1];
  const T* bq = (const T*)d_in[2];
  const T* Wk = (const T*)d_in[3];
  const T* bk = (const T*)d_in[4];
  const T* Wv = (const T*)d_in[5];
  const T* bv = (const T*)d_in[6];
  const T* Wo = (const T*)d_in[7];
  const T* bo = (const T*)d_in[8];
  const T* ls = (const T*)d_in[9];
  const T* gs = (const T*)d_in[10];

  T* out0   = (T*)d_out;
  T* attn_l = out0 + (size_t)B * L * D;
  T* attn_g = attn_l + (size_t)B * LH * L * L;

  proj_qkv_kernel<T><<<dim3((B * L) / 64, 48), 256, 0, stream>>>(
      flag, x, Wq, bq, Wk, bk, Wv, bv, Q, K, V);
  attn_kernel<T><<<dim3(L / 64, H, B), 256, 0, stream>>>(
      flag, Q, K, V, ls, gs, attn_l, attn_g, AO);
  out_proj_kernel<T><<<dim3((B * L) / 64, D / 64), 256, 0, stream>>>(
      flag, AO, Wo, bo, out0);
}

extern "C" void kernel_launch(void* const* d_in, const int* in_sizes, int n_in,
                              void* d_out, int out_size, void* d_ws, size_t ws_size,
                              hipStream_t stream) {
  int* flag = (int*)d_ws;
  detect_dtype_kernel<<<1, 64, 0, stream>>>((const unsigned short*)d_in[0], flag);
  launch_path<float>(d_in, d_out, d_ws, stream);
  launch_path<bf16>(d_in, d_out, d_ws, stream);
}

// Round 3
// 1428.226 us; speedup vs baseline: 4.3657x; 1.2594x over previous
//
#include <hip/hip_runtime.h>
#include <hip/hip_bf16.h>

#define B 2
#define L 2048
#define D 1024
#define H 16
#define HD 64
#define LH 8
#define NEG_INF -1e30f

typedef __hip_bfloat16 bf16;
typedef unsigned short ushort_t;
typedef short bf16x8 __attribute__((ext_vector_type(8)));
typedef float f32x4 __attribute__((ext_vector_type(4)));

#define MFMA16(a, b, c) __builtin_amdgcn_mfma_f32_16x16x32_bf16((a), (b), (c), 0, 0, 0)

template<typename T> struct IsF32;
template<> struct IsF32<float> { static constexpr int value = 1; };
template<> struct IsF32<bf16>  { static constexpr int value = 0; };

__device__ __forceinline__ float ldf(const float* p, size_t i) { return p[i]; }
__device__ __forceinline__ float ldf(const bf16* p, size_t i) { return __bfloat162float(p[i]); }

__device__ __forceinline__ float4 ld4(const float* p, size_t i) {
  return *reinterpret_cast<const float4*>(p + i);
}
__device__ __forceinline__ float4 ld4(const bf16* p, size_t i) {
  ushort4 u = *reinterpret_cast<const ushort4*>(p + i);
  float4 f;
  f.x = __uint_as_float(((unsigned)u.x) << 16);
  f.y = __uint_as_float(((unsigned)u.y) << 16);
  f.z = __uint_as_float(((unsigned)u.z) << 16);
  f.w = __uint_as_float(((unsigned)u.w) << 16);
  return f;
}
__device__ __forceinline__ ushort_t bfh(float v) {
  bf16 h = __float2bfloat16(v);
  return *reinterpret_cast<ushort_t*>(&h);
}
__device__ __forceinline__ float bf2f(ushort_t u) {
  return __uint_as_float(((unsigned)u) << 16);
}
__device__ __forceinline__ void stf(float* p, size_t i, float v) { p[i] = v; }
__device__ __forceinline__ void stf(bf16* p, size_t i, float v) { p[i] = __float2bfloat16(v); }
__device__ __forceinline__ void st4(float* p, size_t i, float4 v) {
  *reinterpret_cast<float4*>(p + i) = v;
}
__device__ __forceinline__ void st4(bf16* p, size_t i, float4 v) {
  ushort4 u;
  u.x = bfh(v.x); u.y = bfh(v.y); u.z = bfh(v.z); u.w = bfh(v.w);
  *reinterpret_cast<ushort4*>(p + i) = u;
}

// XOR-swizzled LDS addressing: 64-ushort (128 B) rows, 8 slots of 8 ushorts (16 B).
// slot' = slot ^ (row & 7)  -> 16B-aligned ds_*_b128, bank-conflict-free floor.
__device__ __forceinline__ int swz(int row, int slot) {
  return row * 64 + (((slot ^ (row & 7)) & 7) << 3);
}
__device__ __forceinline__ int swzc(int row, int c) {   // per-ushort column c
  return row * 64 + (((((c >> 3) ^ row) & 7) << 3) | (c & 7));
}

// Runtime dtype detection: fp32 data reinterpreted as u16 pairs shows large
// "exponent" fields in low halves with prob ~1/3; bf16 N(0,1) never does.
__global__ void detect_dtype_kernel(const unsigned short* __restrict__ x,
                                    int* __restrict__ flag) {
  int bad = 0;
  for (int i = threadIdx.x; i < 1024; i += 64) {
    if (((x[i] >> 7) & 0xFF) >= 170) bad = 1;
  }
  unsigned long long m = __ballot(bad);
  if (threadIdx.x == 0) *flag = (m != 0ULL) ? 1 : 0;
}

// ---------------- prep: split fp32 array into bf16 hi/lo planes ----------------
__global__ __launch_bounds__(256)
void split_f32_kernel(const int* __restrict__ flag, int want,
                      const float* __restrict__ in,
                      ushort_t* __restrict__ hp, ushort_t* __restrict__ lp, int n4) {
  if (*flag != want) return;
  int i = blockIdx.x * 256 + threadIdx.x;
  const int stride = gridDim.x * 256;
  for (; i < n4; i += stride) {
    float4 v = *reinterpret_cast<const float4*>(in + 4 * (size_t)i);
    ushort4 h, l;
    h.x = bfh(v.x); l.x = bfh(v.x - bf2f(h.x));
    h.y = bfh(v.y); l.y = bfh(v.y - bf2f(h.y));
    h.z = bfh(v.z); l.z = bfh(v.z - bf2f(h.z));
    h.w = bfh(v.w); l.w = bfh(v.w - bf2f(h.w));
    *reinterpret_cast<ushort4*>(hp + 4 * (size_t)i) = h;
    *reinterpret_cast<ushort4*>(lp + 4 * (size_t)i) = l;
  }
}

// ---------------- prep: transpose W [K][N] -> Wt [N][K], split to bf16 hi/lo ----
// grid (16, 16, nmats), block 256. per-mat planes: h @ base+z*2M, l @ +1M (ushorts)
template<typename T>
__global__ __launch_bounds__(256)
void transW_kernel(const int* __restrict__ flag,
                   const T* __restrict__ W0, const T* __restrict__ W1,
                   const T* __restrict__ W2, ushort_t* __restrict__ base) {
  if (*flag != IsF32<T>::value) return;
  const T* W = blockIdx.z == 0 ? W0 : (blockIdx.z == 1 ? W1 : W2);
  ushort_t* hp = base + (size_t)blockIdx.z * 2097152;
  ushort_t* lp = hp + 1048576;
  __shared__ float ts[64][69];
  const int k0 = blockIdx.x * 64, n0 = blockIdx.y * 64;
  const int t = threadIdx.x;
  #pragma unroll
  for (int p = 0; p < 4; ++p) {
    int r = p * 16 + (t >> 4);
    int c = (t & 15) * 4;
    float4 v = ld4(W, (size_t)(k0 + r) * D + n0 + c);
    ts[r][c] = v.x; ts[r][c + 1] = v.y; ts[r][c + 2] = v.z; ts[r][c + 3] = v.w;
  }
  __syncthreads();
  #pragma unroll
  for (int p = 0; p < 4; ++p) {
    int n = p * 16 + (t >> 4);
    int k4 = (t & 15) * 4;
    ushort4 h, l;
    float a0 = ts[k4][n], a1 = ts[k4 + 1][n], a2 = ts[k4 + 2][n], a3 = ts[k4 + 3][n];
    h.x = bfh(a0); l.x = bfh(a0 - bf2f(h.x));
    h.y = bfh(a1); l.y = bfh(a1 - bf2f(h.y));
    h.z = bfh(a2); l.z = bfh(a2 - bf2f(h.z));
    h.w = bfh(a3); l.w = bfh(a3 - bf2f(h.w));
    size_t o = (size_t)(n0 + n) * D + k0 + k4;
    *reinterpret_cast<ushort4*>(hp + o) = h;
    if (IsF32<T>::value) *reinterpret_cast<ushort4*>(lp + o) = l;
  }
}

// ---------------- Kernel 1: fused QKV projection (split-bf16 MFMA GEMM) --------
// 1536 blocks of 256 (XCD-swizzled). Per wave: 16 tokens x 128 cols. Writes
// Q/K split planes [B,H,L,HD] and V TRANSPOSED split planes [B,H,HD,L].
template<typename T, int NSA, int NSB>
__global__ __launch_bounds__(256)
void proj_kernel(const int* __restrict__ flag,
                 const ushort_t* __restrict__ xA, const ushort_t* __restrict__ xAl,
                 const ushort_t* __restrict__ wbase,
                 const T* __restrict__ bq, const T* __restrict__ bk,
                 const T* __restrict__ bv,
                 ushort_t* __restrict__ qh, ushort_t* __restrict__ ql,
                 ushort_t* __restrict__ kh, ushort_t* __restrict__ kl,
                 ushort_t* __restrict__ vth, ushort_t* __restrict__ vtl) {
  if (*flag != IsF32<T>::value) return;
  const int bid = blockIdx.x;
  const int xcd = bid & 7, slot = bid >> 3;       // 192 slots
  const int cm = xcd + 8 * (slot >> 6);           // 0..23 (z, coltile)
  const int z = cm >> 3, ct = cm & 7;
  const int strip = slot & 63;
  const int col0 = ct * 128;
  const int lane = threadIdx.x & 63, w = threadIdx.x >> 6;
  const int t0 = strip * 64 + w * 16;
  const int m = lane & 15, hi = lane >> 4;
  const ushort_t* wh = wbase + (size_t)z * 2097152;
  const ushort_t* wl = wh + 1048576;
  const T* bias = z == 0 ? bq : (z == 1 ? bk : bv);

  f32x4 acc[8] = {};
  const size_t arow = (size_t)(t0 + m) * D + hi * 8;
  for (int kc = 0; kc < 32; ++kc) {
    const int ko = kc * 32;
    bf16x8 ah = *reinterpret_cast<const bf16x8*>(xA + arow + ko);
    bf16x8 al;
    if (NSA == 2) al = *reinterpret_cast<const bf16x8*>(xAl + arow + ko);
    #pragma unroll
    for (int nt = 0; nt < 8; ++nt) {
      const size_t bo_ = (size_t)(col0 + nt * 16 + m) * D + ko + hi * 8;
      bf16x8 bhf = *reinterpret_cast<const bf16x8*>(wh + bo_);
      acc[nt] = MFMA16(ah, bhf, acc[nt]);
      if (NSB == 2) {
        bf16x8 blf = *reinterpret_cast<const bf16x8*>(wl + bo_);
        acc[nt] = MFMA16(ah, blf, acc[nt]);
      }
      if (NSA == 2) acc[nt] = MFMA16(al, bhf, acc[nt]);
    }
  }
  const int bb = t0 >> 11, lloc0 = t0 & (L - 1);
  #pragma unroll
  for (int nt = 0; nt < 8; ++nt) {
    const int col = col0 + nt * 16 + m;
    const int hh = col >> 6, d = col & 63;
    const float bv_ = ldf(bias, (size_t)col);
    if (z == 2) {
      ushort4 hv, lv;
      float v0 = acc[nt][0] + bv_, v1 = acc[nt][1] + bv_;
      float v2 = acc[nt][2] + bv_, v3 = acc[nt][3] + bv_;
      hv.x = bfh(v0); lv.x = bfh(v0 - bf2f(hv.x));
      hv.y = bfh(v1); lv.y = bfh(v1 - bf2f(hv.y));
      hv.z = bfh(v2); lv.z = bfh(v2 - bf2f(hv.z));
      hv.w = bfh(v3); lv.w = bfh(v3 - bf2f(hv.w));
      const size_t o = ((size_t)(bb * H + hh) * HD + d) * L + lloc0 + 4 * hi;
      *reinterpret_cast<ushort4*>(vth + o) = hv;
      *reinterpret_cast<ushort4*>(vtl + o) = lv;
    } else {
      ushort_t* oh = z == 0 ? qh : kh;
      ushort_t* ol = z == 0 ? ql : kl;
      #pragma unroll
      for (int r = 0; r < 4; ++r) {
        const int tok = lloc0 + 4 * hi + r;
        float v = acc[nt][r] + bv_;
        const size_t o = ((size_t)(bb * H + hh) * L + tok) * HD + d;
        ushort_t hu = bfh(v);
        oh[o] = hu; ol[o] = bfh(v - bf2f(hu));
      }
    }
  }
}

// ---------------- Kernel 2: attention (split-bf16 MFMA, flash 2-pass) ----------
// 1024 blocks of 256 (XCD-swizzled: same-head q-strips share an XCD's L2).
// Block = 64 q-rows (4 waves x 16). K/V staged in swizzled LDS; P transposed
// through the K-LDS region (reused). Probs written normalized; AO fp32.
template<typename T>
__global__ __launch_bounds__(256)
void attn_kernel(const int* __restrict__ flag,
                 const ushort_t* __restrict__ Qh_g, const ushort_t* __restrict__ Ql_g,
                 const ushort_t* __restrict__ Kh_g, const ushort_t* __restrict__ Kl_g,
                 const ushort_t* __restrict__ Vth_g, const ushort_t* __restrict__ Vtl_g,
                 const T* __restrict__ lsp, const T* __restrict__ gsp,
                 T* __restrict__ attn_l, T* __restrict__ attn_g,
                 float* __restrict__ AO) {
  if (*flag != IsF32<T>::value) return;
  const int bid = blockIdx.x;
  const int xcd = bid & 7, slot = bid >> 3;       // 128 slots
  const int bhg = xcd + 8 * (slot >> 5);          // 0..31 (b,h)
  const int strip = slot & 31;
  const int bb = bhg >> 4, h = bhg & 15;
  const int q0 = strip * 64;
  const int lane = threadIdx.x & 63, w = threadIdx.x >> 6;
  const int m = lane & 15, hi = lane >> 4;

  const bool is_local = h < LH;
  const float cscale =
      (is_local ? ldf(lsp, (size_t)0) : ldf(gsp, (size_t)0)) * 0.125f;
  const size_t bh_off = ((size_t)bb * H + h) * L * HD;
  const ushort_t* Qh = Qh_g + bh_off;
  const ushort_t* Ql = Ql_g + bh_off;
  const ushort_t* Kh = Kh_g + bh_off;
  const ushort_t* Kl = Kl_g + bh_off;
  const ushort_t* Vh = Vth_g + bh_off;   // [HD][L] per (b,h)
  const ushort_t* Vl = Vtl_g + bh_off;

  // 4 planes x 64 rows x 64 ushorts (128B rows, XOR slot swizzle) = 32 KB
  __shared__ ushort_t KsH[4096], KsL[4096], VsH[4096], VsL[4096];

  // staging map: thread -> (row, 2 slots) ; 32 contiguous bytes per plane
  const int srow = threadIdx.x >> 2;        // 0..63
  const int sl0  = (threadIdx.x & 3) * 2;   // slots {sl0, sl0+1}

  // Q fragments (persist whole kernel)
  bf16x8 qfh[2], qfl[2];
  {
    const size_t qb = (size_t)(q0 + 16 * w + m) * HD + hi * 8;
    qfh[0] = *reinterpret_cast<const bf16x8*>(Qh + qb);
    qfh[1] = *reinterpret_cast<const bf16x8*>(Qh + qb + 32);
    qfl[0] = *reinterpret_cast<const bf16x8*>(Ql + qb);
    qfl[1] = *reinterpret_cast<const bf16x8*>(Ql + qb + 32);
  }

  float m_[4], l_[4], invl[4];
  #pragma unroll
  for (int r = 0; r < 4; ++r) { m_[r] = NEG_INF; l_[r] = 0.f; }

  const int nkt = is_local ? (strip + 1) : (L / 64);
  const int dtile = strip;
  f32x4 o_[4] = {};
  T* aout = is_local ? attn_l : attn_g;
  const size_t arowW =
      ((size_t)(bb * LH + (is_local ? h : h - LH)) * L + q0 + 16 * w) * L;

  for (int pass = 0; pass < 2; ++pass) {
    for (int kt = 0; kt < nkt; ++kt) {
      {
        const ushort_t* kr  = Kh + (size_t)(kt * 64 + srow) * HD + sl0 * 8;
        const ushort_t* krl = Kl + (size_t)(kt * 64 + srow) * HD + sl0 * 8;
        *reinterpret_cast<uint4*>(&KsH[swz(srow, sl0)])     = *reinterpret_cast<const uint4*>(kr);
        *reinterpret_cast<uint4*>(&KsH[swz(srow, sl0 + 1)]) = *reinterpret_cast<const uint4*>(kr + 8);
        *reinterpret_cast<uint4*>(&KsL[swz(srow, sl0)])     = *reinterpret_cast<const uint4*>(krl);
        *reinterpret_cast<uint4*>(&KsL[swz(srow, sl0 + 1)]) = *reinterpret_cast<const uint4*>(krl + 8);
        if (pass) {
          const ushort_t* vr  = Vh + (size_t)srow * L + kt * 64 + sl0 * 8;
          const ushort_t* vrl = Vl + (size_t)srow * L + kt * 64 + sl0 * 8;
          *reinterpret_cast<uint4*>(&VsH[swz(srow, sl0)])     = *reinterpret_cast<const uint4*>(vr);
          *reinterpret_cast<uint4*>(&VsH[swz(srow, sl0 + 1)]) = *reinterpret_cast<const uint4*>(vr + 8);
          *reinterpret_cast<uint4*>(&VsL[swz(srow, sl0)])     = *reinterpret_cast<const uint4*>(vrl);
          *reinterpret_cast<uint4*>(&VsL[swz(srow, sl0 + 1)]) = *reinterpret_cast<const uint4*>(vrl + 8);
        }
      }
      __syncthreads();

      f32x4 s[4] = {};
      #pragma unroll
      for (int nt = 0; nt < 4; ++nt) {
        #pragma unroll
        for (int kc = 0; kc < 2; ++kc) {
          bf16x8 kbh = *reinterpret_cast<const bf16x8*>(&KsH[swz(nt * 16 + m, kc * 4 + hi)]);
          bf16x8 kbl = *reinterpret_cast<const bf16x8*>(&KsL[swz(nt * 16 + m, kc * 4 + hi)]);
          s[nt] = MFMA16(qfh[kc], kbh, s[nt]);
          s[nt] = MFMA16(qfh[kc], kbl, s[nt]);
          s[nt] = MFMA16(qfl[kc], kbh, s[nt]);
        }
      }
      const bool dg = is_local && (kt == dtile);
      #pragma unroll
      for (int nt = 0; nt < 4; ++nt)
        #pragma unroll
        for (int r = 0; r < 4; ++r) {
          float v = s[nt][r] * cscale;
          if (dg && (kt * 64 + nt * 16 + m > q0 + 16 * w + 4 * hi + r)) v = NEG_INF;
          s[nt][r] = v;
        }

      if (pass == 0) {
        #pragma unroll
        for (int r = 0; r < 4; ++r) {
          float tm = fmaxf(fmaxf(s[0][r], s[1][r]), fmaxf(s[2][r], s[3][r]));
          tm = fmaxf(tm, __shfl_xor(tm, 1, 64));
          tm = fmaxf(tm, __shfl_xor(tm, 2, 64));
          tm = fmaxf(tm, __shfl_xor(tm, 4, 64));
          tm = fmaxf(tm, __shfl_xor(tm, 8, 64));
          float mn = fmaxf(m_[r], tm);
          float sum = __expf(s[0][r] - mn) + __expf(s[1][r] - mn) +
                      __expf(s[2][r] - mn) + __expf(s[3][r] - mn);
          sum += __shfl_xor(sum, 1, 64);
          sum += __shfl_xor(sum, 2, 64);
          sum += __shfl_xor(sum, 4, 64);
          sum += __shfl_xor(sum, 8, 64);
          l_[r] = l_[r] * __expf(m_[r] - mn) + sum;
          m_[r] = mn;
        }
        __syncthreads();
      } else {
        __syncthreads();   // all QK reads of Ks complete before P overwrites it
        #pragma unroll
        for (int nt = 0; nt < 4; ++nt)
          #pragma unroll
          for (int r = 0; r < 4; ++r) {
            float p = __expf(s[nt][r] - m_[r]) * invl[r];
            stf(aout, arowW + (size_t)(4 * hi + r) * L + kt * 64 + nt * 16 + m, p);
            const int pi = swzc(16 * w + 4 * hi + r, nt * 16 + m);
            ushort_t hu = bfh(p);
            KsH[pi] = hu;
            KsL[pi] = bfh(p - bf2f(hu));
          }
        __syncthreads();
        bf16x8 pfh[2], pfl[2];
        #pragma unroll
        for (int kc = 0; kc < 2; ++kc) {
          pfh[kc] = *reinterpret_cast<const bf16x8*>(&KsH[swz(16 * w + m, kc * 4 + hi)]);
          pfl[kc] = *reinterpret_cast<const bf16x8*>(&KsL[swz(16 * w + m, kc * 4 + hi)]);
        }
        #pragma unroll
        for (int dt = 0; dt < 4; ++dt) {
          #pragma unroll
          for (int kc = 0; kc < 2; ++kc) {
            bf16x8 vfh = *reinterpret_cast<const bf16x8*>(&VsH[swz(dt * 16 + m, kc * 4 + hi)]);
            bf16x8 vfl = *reinterpret_cast<const bf16x8*>(&VsL[swz(dt * 16 + m, kc * 4 + hi)]);
            o_[dt] = MFMA16(pfh[kc], vfh, o_[dt]);
            o_[dt] = MFMA16(pfh[kc], vfl, o_[dt]);
            o_[dt] = MFMA16(pfl[kc], vfh, o_[dt]);
          }
        }
        __syncthreads();
      }
    }
    if (pass == 0) {
      #pragma unroll
      for (int r = 0; r < 4; ++r) invl[r] = 1.0f / l_[r];
    }
  }

  // fully-masked region of causal heads: probs exactly 0
  if (is_local) {
    const float4 z4 = make_float4(0.f, 0.f, 0.f, 0.f);
    #pragma unroll
    for (int r = 0; r < 4; ++r) {
      const size_t rowo = arowW + (size_t)(4 * hi + r) * L;
      for (int c = nkt * 64 + m * 4; c < L; c += 64) st4(aout, rowo + c, z4);
    }
  }

  // AO [B,L,D] fp32
  #pragma unroll
  for (int dt = 0; dt < 4; ++dt)
    #pragma unroll
    for (int r = 0; r < 4; ++r)
      AO[((size_t)bb * L + q0 + 16 * w + 4 * hi + r) * D + h * HD + dt * 16 + m] =
          o_[dt][r];
}

// ---------------- Kernel 3: output projection (split-bf16 MFMA GEMM) ----------
template<typename T, int NSB>
__global__ __launch_bounds__(256)
void out_proj_kernel(const int* __restrict__ flag,
                     const ushort_t* __restrict__ ah_, const ushort_t* __restrict__ al_,
                     const ushort_t* __restrict__ wh, const ushort_t* __restrict__ wl,
                     const T* __restrict__ bo, T* __restrict__ out) {
  if (*flag != IsF32<T>::value) return;
  const int bid = blockIdx.x;                      // 512 blocks
  const int xcd = bid & 7, slot = bid >> 3;        // 64 slots
  const int col0 = xcd * 128;
  const int strip = slot;
  const int lane = threadIdx.x & 63, w = threadIdx.x >> 6;
  const int t0 = strip * 64 + w * 16;
  const int m = lane & 15, hi = lane >> 4;

  f32x4 acc[8] = {};
  const size_t arow = (size_t)(t0 + m) * D + hi * 8;
  for (int kc = 0; kc < 32; ++kc) {
    const int ko = kc * 32;
    bf16x8 ah = *reinterpret_cast<const bf16x8*>(ah_ + arow + ko);
    bf16x8 al = *reinterpret_cast<const bf16x8*>(al_ + arow + ko);
    #pragma unroll
    for (int nt = 0; nt < 8; ++nt) {
      const size_t bo_ = (size_t)(col0 + nt * 16 + m) * D + ko + hi * 8;
      bf16x8 bhf = *reinterpret_cast<const bf16x8*>(wh + bo_);
      acc[nt] = MFMA16(ah, bhf, acc[nt]);
      if (NSB == 2) {
        bf16x8 blf = *reinterpret_cast<const bf16x8*>(wl + bo_);
        acc[nt] = MFMA16(ah, blf, acc[nt]);
      }
      acc[nt] = MFMA16(al, bhf, acc[nt]);
    }
  }
  #pragma unroll
  for (int nt = 0; nt < 8; ++nt) {
    const int col = col0 + nt * 16 + m;
    const float bv_ = ldf(bo, (size_t)col);
    #pragma unroll
    for (int r = 0; r < 4; ++r) {
      const int tok = t0 + 4 * hi + r;
      stf(out, (size_t)tok * D + col, acc[nt][r] + bv_);
    }
  }
}

template<typename T>
static void launch_path(void* const* d_in, void* d_out, void* d_ws, hipStream_t stream) {
  const int want = IsF32<T>::value;
  const int* flag = (const int*)d_ws;
  ushort_t* Qh = (ushort_t*)((char*)d_ws + 256);
  ushort_t* Ql = Qh + 4194304;
  ushort_t* Kh = Ql + 4194304;
  ushort_t* Kl = Kh + 4194304;
  ushort_t* Vth = Kl + 4194304;
  ushort_t* Vtl = Vth + 4194304;
  float* AO = (float*)(Vtl + 4194304);        // 16.8 MB fp32; total ws = 67.1 MB
  // post-attention reuse of dead regions:
  ushort_t* AOh = Qh;                          // region A
  ushort_t* AOl = Ql;
  ushort_t* Woth = Kh;                         // region B
  ushort_t* Wotl = Kh + 1048576;

  const T* x  = (const T*)d_in[0];
  const T* Wq = (const T*)d_in[1];
  const T* bq = (const T*)d_in[2];
  const T* Wk = (const T*)d_in[3];
  const T* bk = (const T*)d_in[4];
  const T* Wv = (const T*)d_in[5];
  const T* bv = (const T*)d_in[6];
  const T* Wo = (const T*)d_in[7];
  const T* bo = (const T*)d_in[8];
  const T* ls = (const T*)d_in[9];
  const T* gs = (const T*)d_in[10];

  T* out0   = (T*)d_out;
  T* attn_l = out0 + (size_t)B * L * D;
  T* attn_g = attn_l + (size_t)B * LH * L * L;
  // scratch inside the not-yet-written attn_g output region (written later by attn)
  ushort_t* xh  = (ushort_t*)attn_g;
  ushort_t* xl  = xh + 4194304;
  ushort_t* Wt3 = xh + 8388608;                // 3 mats x (h,l) planes

  constexpr int NSA = IsF32<T>::value ? 2 : 1;
  constexpr int NSB = IsF32<T>::value ? 2 : 1;

  if (IsF32<T>::value)
    split_f32_kernel<<<1024, 256, 0, stream>>>(flag, want, (const float*)x, xh, xl, 1048576);
  transW_kernel<T><<<dim3(16, 16, 3), 256, 0, stream>>>(flag, Wq, Wk, Wv, Wt3);
  const ushort_t* xA = IsF32<T>::value ? (const ushort_t*)xh : (const ushort_t*)x;
  proj_kernel<T, NSA, NSB><<<1536, 256, 0, stream>>>(
      flag, xA, xl, Wt3, bq, bk, bv, Qh, Ql, Kh, Kl, Vth, Vtl);
  attn_kernel<T><<<1024, 256, 0, stream>>>(
      flag, Qh, Ql, Kh, Kl, Vth, Vtl, ls, gs, attn_l, attn_g, AO);
  split_f32_kernel<<<1024, 256, 0, stream>>>(flag, want, AO, AOh, AOl, 1048576);
  transW_kernel<T><<<dim3(16, 16, 1), 256, 0, stream>>>(flag, Wo, Wo, Wo, Woth);
  out_proj_kernel<T, NSB><<<512, 256, 0, stream>>>(flag, AOh, AOl, Woth, Wotl, bo, out0);
}

extern "C" void kernel_launch(void* const* d_in, const int* in_sizes, int n_in,
                              void* d_out, int out_size, void* d_ws, size_t ws_size,
                              hipStream_t stream) {
  int* flag = (int*)d_ws;
  detect_dtype_kernel<<<1, 64, 0, stream>>>((const unsigned short*)d_in[0], flag);
  launch_path<float>(d_in, d_out, d_ws, stream);
  launch_path<bf16>(d_in, d_out, d_ws, stream);
}

// Round 4
// 1305.957 us; speedup vs baseline: 4.7744x; 1.0936x over previous
//
#include <hip/hip_runtime.h>
#include <hip/hip_bf16.h>

#define B 2
#define L 2048
#define D 1024
#define H 16
#define HD 64
#define LH 8
#define NEG_INF -1e30f

typedef __hip_bfloat16 bf16;
typedef unsigned short ushort_t;
typedef short bf16x8 __attribute__((ext_vector_type(8)));
typedef unsigned short us8 __attribute__((ext_vector_type(8)));
typedef float f32x4 __attribute__((ext_vector_type(4)));

#define MFMA16(a, b, c) __builtin_amdgcn_mfma_f32_16x16x32_bf16((a), (b), (c), 0, 0, 0)

#if defined(__has_builtin)
#if __has_builtin(__builtin_amdgcn_global_load_lds)
#define HAVE_GLOAD_LDS 1
#endif
#endif

template<typename T> struct IsF32;
template<> struct IsF32<float> { static constexpr int value = 1; };
template<> struct IsF32<bf16>  { static constexpr int value = 0; };

__device__ __forceinline__ float ldf(const float* p, size_t i) { return p[i]; }
__device__ __forceinline__ float ldf(const bf16* p, size_t i) { return __bfloat162float(p[i]); }

__device__ __forceinline__ float4 ld4(const float* p, size_t i) {
  return *reinterpret_cast<const float4*>(p + i);
}
__device__ __forceinline__ float4 ld4(const bf16* p, size_t i) {
  ushort4 u = *reinterpret_cast<const ushort4*>(p + i);
  float4 f;
  f.x = __uint_as_float(((unsigned)u.x) << 16);
  f.y = __uint_as_float(((unsigned)u.y) << 16);
  f.z = __uint_as_float(((unsigned)u.z) << 16);
  f.w = __uint_as_float(((unsigned)u.w) << 16);
  return f;
}
__device__ __forceinline__ ushort_t bfh(float v) {
  bf16 h = __float2bfloat16(v);
  return *reinterpret_cast<ushort_t*>(&h);
}
__device__ __forceinline__ float bf2f(ushort_t u) {
  return __uint_as_float(((unsigned)u) << 16);
}
__device__ __forceinline__ void stf(float* p, size_t i, float v) { p[i] = v; }
__device__ __forceinline__ void stf(bf16* p, size_t i, float v) { p[i] = __float2bfloat16(v); }

// XOR-swizzled LDS addressing: 64-ushort (128 B) rows, 8 slots of 8 ushorts (16 B).
__device__ __forceinline__ int swz(int row, int slot) {
  return row * 64 + (((slot ^ (row & 7)) & 7) << 3);
}
__device__ __forceinline__ int swzc(int row, int c) {   // per-ushort column c
  return row * 64 + (((((c >> 3) ^ row) & 7) << 3) | (c & 7));
}

#if defined(HAVE_GLOAD_LDS)
__device__ __forceinline__ void gload_lds16(const ushort_t* src, ushort_t* dst) {
  __builtin_amdgcn_global_load_lds(
      (const __attribute__((address_space(1))) unsigned int*)src,
      (__attribute__((address_space(3))) unsigned int*)dst, 16, 0, 0);
}
#endif

// Stage a 64x64 ushort tile (rows 16w..16w+15 per wave) into swizzled LDS.
// LDS dest is linear (row*64 + (l&7)*8); the XOR swizzle is applied to the
// GLOBAL source slot (inverse-involution), per rule #21.
__device__ __forceinline__ void stage64(const ushort_t* g, size_t gstride,
                                        ushort_t* lds, int w, int ln) {
  #pragma unroll
  for (int c = 0; c < 2; ++c) {
    const int row = 16 * w + 8 * c + (ln >> 3);
    const int slot = ((ln & 7) ^ row) & 7;
    const ushort_t* src = g + (size_t)row * gstride + slot * 8;
#if defined(HAVE_GLOAD_LDS)
    gload_lds16(src, lds + (size_t)(16 * w + 8 * c) * 64);
#else
    *reinterpret_cast<uint4*>(&lds[row * 64 + (ln & 7) * 8]) =
        *reinterpret_cast<const uint4*>(src);
#endif
  }
}

// Runtime dtype detection: fp32 data reinterpreted as u16 pairs shows large
// "exponent" fields in low halves with prob ~1/3; bf16 N(0,1) never does.
__global__ void detect_dtype_kernel(const unsigned short* __restrict__ x,
                                    int* __restrict__ flag) {
  int bad = 0;
  for (int i = threadIdx.x; i < 1024; i += 64) {
    if (((x[i] >> 7) & 0xFF) >= 170) bad = 1;
  }
  unsigned long long m = __ballot(bad);
  if (threadIdx.x == 0) *flag = (m != 0ULL) ? 1 : 0;
}

// ---------------- prep: split fp32 array into bf16 hi/lo planes ----------------
__global__ __launch_bounds__(256)
void split_f32_kernel(const int* __restrict__ flag, int want,
                      const float* __restrict__ in,
                      ushort_t* __restrict__ hp, ushort_t* __restrict__ lp, int n4) {
  if (*flag != want) return;
  int i = blockIdx.x * 256 + threadIdx.x;
  const int stride = gridDim.x * 256;
  for (; i < n4; i += stride) {
    float4 v = *reinterpret_cast<const float4*>(in + 4 * (size_t)i);
    ushort4 h, l;
    h.x = bfh(v.x); l.x = bfh(v.x - bf2f(h.x));
    h.y = bfh(v.y); l.y = bfh(v.y - bf2f(h.y));
    h.z = bfh(v.z); l.z = bfh(v.z - bf2f(h.z));
    h.w = bfh(v.w); l.w = bfh(v.w - bf2f(h.w));
    *reinterpret_cast<ushort4*>(hp + 4 * (size_t)i) = h;
    *reinterpret_cast<ushort4*>(lp + 4 * (size_t)i) = l;
  }
}

// ---------------- prep: transpose W [K][N] -> Wt [N][K], split to bf16 hi/lo ----
// lo plane written only for fp32 path AND blockIdx.z < lo_upto.
template<typename T>
__global__ __launch_bounds__(256)
void transW_kernel(const int* __restrict__ flag,
                   const T* __restrict__ W0, const T* __restrict__ W1,
                   const T* __restrict__ W2, ushort_t* __restrict__ base,
                   int lo_upto) {
  if (*flag != IsF32<T>::value) return;
  const T* W = blockIdx.z == 0 ? W0 : (blockIdx.z == 1 ? W1 : W2);
  ushort_t* hp = base + (size_t)blockIdx.z * 2097152;
  ushort_t* lp = hp + 1048576;
  const bool wl_ = IsF32<T>::value && ((int)blockIdx.z < lo_upto);
  __shared__ float ts[64][69];
  const int k0 = blockIdx.x * 64, n0 = blockIdx.y * 64;
  const int t = threadIdx.x;
  #pragma unroll
  for (int p = 0; p < 4; ++p) {
    int r = p * 16 + (t >> 4);
    int c = (t & 15) * 4;
    float4 v = ld4(W, (size_t)(k0 + r) * D + n0 + c);
    ts[r][c] = v.x; ts[r][c + 1] = v.y; ts[r][c + 2] = v.z; ts[r][c + 3] = v.w;
  }
  __syncthreads();
  #pragma unroll
  for (int p = 0; p < 4; ++p) {
    int n = p * 16 + (t >> 4);
    int k4 = (t & 15) * 4;
    ushort4 h, l;
    float a0 = ts[k4][n], a1 = ts[k4 + 1][n], a2 = ts[k4 + 2][n], a3 = ts[k4 + 3][n];
    h.x = bfh(a0); l.x = bfh(a0 - bf2f(h.x));
    h.y = bfh(a1); l.y = bfh(a1 - bf2f(h.y));
    h.z = bfh(a2); l.z = bfh(a2 - bf2f(h.z));
    h.w = bfh(a3); l.w = bfh(a3 - bf2f(h.w));
    size_t o = (size_t)(n0 + n) * D + k0 + k4;
    *reinterpret_cast<ushort4*>(hp + o) = h;
    if (wl_) *reinterpret_cast<ushort4*>(lp + o) = l;
  }
}

// ---------------- Kernel 1: fused QKV projection (MFMA GEMM) -------------------
// 1536 blocks of 256 (XCD-swizzled; coltile==xcd so weight slabs are L2-local).
// Q,K: 3-product split (fp32 path); V: 1-product. Writes Q/K hi+lo planes
// [B,H,L,HD] and V TRANSPOSED hi plane [B,H,HD,L].
template<typename T, int NSA>
__global__ __launch_bounds__(256)
void proj_kernel(const int* __restrict__ flag,
                 const ushort_t* __restrict__ xA, const ushort_t* __restrict__ xAl,
                 const ushort_t* __restrict__ wbase,
                 const T* __restrict__ bq, const T* __restrict__ bk,
                 const T* __restrict__ bv,
                 ushort_t* __restrict__ qh, ushort_t* __restrict__ ql,
                 ushort_t* __restrict__ kh, ushort_t* __restrict__ kl,
                 ushort_t* __restrict__ vth) {
  if (*flag != IsF32<T>::value) return;
  const int bid = blockIdx.x;
  const int xcd = bid & 7, slot = bid >> 3;       // 192 slots
  const int cm = xcd + 8 * (slot >> 6);           // 0..23 (z, coltile)
  const int z = cm >> 3, ct = cm & 7;
  const int strip = slot & 63;
  const int col0 = ct * 128;
  const int lane = threadIdx.x & 63, w = threadIdx.x >> 6;
  const int t0 = strip * 64 + w * 16;
  const int m = lane & 15, hi = lane >> 4;
  const ushort_t* wh = wbase + (size_t)z * 2097152;
  const ushort_t* wl = wh + 1048576;
  const T* bias = z == 0 ? bq : (z == 1 ? bk : bv);
  const bool full = (NSA == 2) && (z != 2);   // 3-product for Q,K on fp32 path

  f32x4 acc[8] = {};
  const size_t arow = (size_t)(t0 + m) * D + hi * 8;
  for (int kc = 0; kc < 32; ++kc) {
    const int ko = kc * 32;
    bf16x8 ah = *reinterpret_cast<const bf16x8*>(xA + arow + ko);
    bf16x8 al;
    if (full) al = *reinterpret_cast<const bf16x8*>(xAl + arow + ko);
    #pragma unroll
    for (int nt = 0; nt < 8; ++nt) {
      const size_t bo_ = (size_t)(col0 + nt * 16 + m) * D + ko + hi * 8;
      bf16x8 bhf = *reinterpret_cast<const bf16x8*>(wh + bo_);
      acc[nt] = MFMA16(ah, bhf, acc[nt]);
      if (full) {
        bf16x8 blf = *reinterpret_cast<const bf16x8*>(wl + bo_);
        acc[nt] = MFMA16(ah, blf, acc[nt]);
        acc[nt] = MFMA16(al, bhf, acc[nt]);
      }
    }
  }
  const int bb = t0 >> 11, lloc0 = t0 & (L - 1);
  #pragma unroll
  for (int nt = 0; nt < 8; ++nt) {
    const int col = col0 + nt * 16 + m;
    const int hh = col >> 6, d = col & 63;
    const float bv_ = ldf(bias, (size_t)col);
    if (z == 2) {
      ushort4 hv;
    hv.x = bfh(acc[nt][0] + bv_);
      hv.y = bfh(acc[nt][1] + bv_);
      hv.z = bfh(acc[nt][2] + bv_);
      hv.w = bfh(acc[nt][3] + bv_);
      const size_t o = ((size_t)(bb * H + hh) * HD + d) * L + lloc0 + 4 * hi;
      *reinterpret_cast<ushort4*>(vth + o) = hv;
    } else {
      ushort_t* oh = z == 0 ? qh : kh;
      ushort_t* ol = z == 0 ? ql : kl;
      #pragma unroll
      for (int r = 0; r < 4; ++r) {
        const int tok = lloc0 + 4 * hi + r;
        float v = acc[nt][r] + bv_;
        const size_t o = ((size_t)(bb * H + hh) * L + tok) * HD + d;
        ushort_t hu = bfh(v);
        oh[o] = hu; ol[o] = bfh(v - bf2f(hu));
      }
    }
  }
}

// ---------------- Kernel 2: attention (swapped-QK MFMA, flash 2-pass) ----------
// 1024 blocks of 256 (XCD-swizzled). Block = 64 q-rows (4 waves x 16, swapped
// layout: each lane owns one q-row). QK 3-product (fp32-faithful scores);
// PV 1-product. Probs written coalesced from swizzled LDS; AO emitted as bf16.
template<typename T>
__global__ __launch_bounds__(256)
void attn_kernel(const int* __restrict__ flag,
                 const ushort_t* __restrict__ Qh_g, const ushort_t* __restrict__ Ql_g,
                 const ushort_t* __restrict__ Kh_g, const ushort_t* __restrict__ Kl_g,
                 const ushort_t* __restrict__ Vth_g,
                 const T* __restrict__ lsp, const T* __restrict__ gsp,
                 T* __restrict__ attn_l, T* __restrict__ attn_g,
                 ushort_t* __restrict__ AOh) {
  if (*flag != IsF32<T>::value) return;
  const int bid = blockIdx.x;
  const int xcd = bid & 7, slot = bid >> 3;       // 128 slots
  const int bhg = xcd + 8 * (slot >> 5);          // 0..31 (b,h)
  const int strip_raw = slot & 31;
  const int bb = bhg >> 4, h = bhg & 15;
  const bool is_local = h < LH;
  const int strip = is_local ? (31 - strip_raw) : strip_raw;  // long strips first
  const int q0 = strip * 64;
  const int ln = threadIdx.x & 63, w = threadIdx.x >> 6;
  const int m = ln & 15, hi = ln >> 4;

  const float cscale =
      (is_local ? ldf(lsp, (size_t)0) : ldf(gsp, (size_t)0)) * 0.125f;
  const size_t bh_off = ((size_t)bb * H + h) * L * HD;
  const ushort_t* Qhb = Qh_g + bh_off;
  const ushort_t* Qlb = Ql_g + bh_off;
  const ushort_t* Khb = Kh_g + bh_off;
  const ushort_t* Klb = Kl_g + bh_off;
  const ushort_t* Vhb = Vth_g + bh_off;   // [HD][L] per (b,h)

  __shared__ ushort_t KsH[4096], KsL[4096], VsH[4096], Ps[4096];   // 32 KB

  // Q fragments (B-operand; persist whole kernel)
  bf16x8 qfh[2], qfl[2];
  {
    const size_t qb = (size_t)(q0 + 16 * w + m) * HD + hi * 8;
    qfh[0] = *reinterpret_cast<const bf16x8*>(Qhb + qb);
    qfh[1] = *reinterpret_cast<const bf16x8*>(Qhb + qb + 32);
    qfl[0] = *reinterpret_cast<const bf16x8*>(Qlb + qb);
    qfl[1] = *reinterpret_cast<const bf16x8*>(Qlb + qb + 32);
  }

  float m_ = NEG_INF, l_ = 0.f;
  const int nkt = is_local ? (strip + 1) : (L / 64);
  T* aout = is_local ? attn_l : attn_g;
  const size_t arow0 =
      ((size_t)(bb * LH + (is_local ? h : h - LH)) * L + q0) * L;

  // ---------------- pass 1: row max / sum (swapped QK: lane owns q=16w+m) -----
  for (int kt = 0; kt < nkt; ++kt) {
    stage64(Khb + (size_t)(kt * 64) * HD, HD, KsH, w, ln);
    stage64(Klb + (size_t)(kt * 64) * HD, HD, KsL, w, ln);
    __syncthreads();

    f32x4 s[4] = {};
    __builtin_amdgcn_s_setprio(1);
    #pragma unroll
    for (int nt = 0; nt < 4; ++nt) {
      #pragma unroll
      for (int kc = 0; kc < 2; ++kc) {
        bf16x8 kbh = *reinterpret_cast<const bf16x8*>(&KsH[swz(nt * 16 + m, kc * 4 + hi)]);
        bf16x8 kbl = *reinterpret_cast<const bf16x8*>(&KsL[swz(nt * 16 + m, kc * 4 + hi)]);
        s[nt] = MFMA16(kbh, qfh[kc], s[nt]);
        s[nt] = MFMA16(kbl, qfh[kc], s[nt]);
        s[nt] = MFMA16(kbh, qfl[kc], s[nt]);
      }
    }
    __builtin_amdgcn_s_setprio(0);

    const bool dg = is_local && (kt == strip);
    #pragma unroll
    for (int nt = 0; nt < 4; ++nt)
      #pragma unroll
      for (int r = 0; r < 4; ++r) {
        float v = s[nt][r] * cscale;
        if (dg && (nt * 16 + 4 * hi + r > 16 * w + m)) v = NEG_INF;
        s[nt][r] = v;
      }

    float tm = NEG_INF;
    #pragma unroll
    for (int nt = 0; nt < 4; ++nt)
      #pragma unroll
      for (int r = 0; r < 4; ++r) tm = fmaxf(tm, s[nt][r]);
    tm = fmaxf(tm, __shfl_xor(tm, 16, 64));
    tm = fmaxf(tm, __shfl_xor(tm, 32, 64));
    const float mn = fmaxf(m_, tm);
    float sum = 0.f;
    #pragma unroll
    for (int nt = 0; nt < 4; ++nt)
      #pragma unroll
      for (int r = 0; r < 4; ++r) sum += __expf(s[nt][r] - mn);
    sum += __shfl_xor(sum, 16, 64);
    sum += __shfl_xor(sum, 32, 64);
    l_ = l_ * __expf(m_ - mn) + sum;
    m_ = mn;
    __syncthreads();
  }

  const float invl = 1.0f / l_;
  f32x4 o_[4] = {};

  // ---------------- pass 2: recompute, normalize, write probs, PV -------------
  for (int kt = 0; kt < nkt; ++kt) {
    stage64(Khb + (size_t)(kt * 64) * HD, HD, KsH, w, ln);
    stage64(Klb + (size_t)(kt * 64) * HD, HD, KsL, w, ln);
    stage64(Vhb + (size_t)(kt * 64), L, VsH, w, ln);
    __syncthreads();

    f32x4 s[4] = {};
    __builtin_amdgcn_s_setprio(1);
    #pragma unroll
    for (int nt = 0; nt < 4; ++nt) {
      #pragma unroll
      for (int kc = 0; kc < 2; ++kc) {
        bf16x8 kbh = *reinterpret_cast<const bf16x8*>(&KsH[swz(nt * 16 + m, kc * 4 + hi)]);
        bf16x8 kbl = *reinterpret_cast<const bf16x8*>(&KsL[swz(nt * 16 + m, kc * 4 + hi)]);
        s[nt] = MFMA16(kbh, qfh[kc], s[nt]);
        s[nt] = MFMA16(kbl, qfh[kc], s[nt]);
        s[nt] = MFMA16(kbh, qfl[kc], s[nt]);
      }
    }
    __builtin_amdgcn_s_setprio(0);

    const bool dg = is_local && (kt == strip);
    // p = exp(s - m)/l, pack 4 consecutive k per ds_write_b64 into Ps[q][k]
    #pragma unroll
    for (int nt = 0; nt < 4; ++nt) {
      float v0 = s[nt][0] * cscale, v1 = s[nt][1] * cscale;
      float v2 = s[nt][2] * cscale, v3 = s[nt][3] * cscale;
      if (dg) {
        const int kb = nt * 16 + 4 * hi, qq = 16 * w + m;
        if (kb + 0 > qq) v0 = NEG_INF;
        if (kb + 1 > qq) v1 = NEG_INF;
        if (kb + 2 > qq) v2 = NEG_INF;
        if (kb + 3 > qq) v3 = NEG_INF;
      }
      ushort4 pk;
      pk.x = bfh(__expf(v0 - m_) * invl);
      pk.y = bfh(__expf(v1 - m_) * invl);
      pk.z = bfh(__expf(v2 - m_) * invl);
      pk.w = bfh(__expf(v3 - m_) * invl);
      *reinterpret_cast<ushort4*>(&Ps[swzc(16 * w + m, nt * 16 + 4 * hi)]) = pk;
    }

    // PV (1-product): A = P rows (own-wave), B = V^T rows — within-wave LDS dep
    __builtin_amdgcn_s_setprio(1);
    bf16x8 pf0 = *reinterpret_cast<const bf16x8*>(&Ps[swz(16 * w + m, hi)]);
    bf16x8 pf1 = *reinterpret_cast<const bf16x8*>(&Ps[swz(16 * w + m, 4 + hi)]);
    #pragma unroll
    for (int dt = 0; dt < 4; ++dt) {
      bf16x8 vf0 = *reinterpret_cast<const bf16x8*>(&VsH[swz(dt * 16 + m, hi)]);
      bf16x8 vf1 = *reinterpret_cast<const bf16x8*>(&VsH[swz(dt * 16 + m, 4 + hi)]);
      o_[dt] = MFMA16(pf0, vf0, o_[dt]);
      o_[dt] = MFMA16(pf1, vf1, o_[dt]);
    }
    __builtin_amdgcn_s_setprio(0);

    // coalesced prob write: wave reads its own 16 Ps rows, 128-B global segments
    {
      const int pr = 16 * w + (ln >> 2);
      const int cs = (ln & 3) * 2;
      us8 v0 = *reinterpret_cast<const us8*>(&Ps[swz(pr, cs)]);
      us8 v1 = *reinterpret_cast<const us8*>(&Ps[swz(pr, cs + 1)]);
      const size_t gi = arow0 + (size_t)pr * L + (size_t)(kt * 64 + (ln & 3) * 16);
      if constexpr (IsF32<T>::value) {
        float* dst = (float*)aout + gi;
        *reinterpret_cast<float4*>(dst + 0) =
            make_float4(bf2f(v0[0]), bf2f(v0[1]), bf2f(v0[2]), bf2f(v0[3]));
        *reinterpret_cast<float4*>(dst + 4) =
            make_float4(bf2f(v0[4]), bf2f(v0[5]), bf2f(v0[6]), bf2f(v0[7]));
        *reinterpret_cast<float4*>(dst + 8) =
            make_float4(bf2f(v1[0]), bf2f(v1[1]), bf2f(v1[2]), bf2f(v1[3]));
        *reinterpret_cast<float4*>(dst + 12) =
            make_float4(bf2f(v1[4]), bf2f(v1[5]), bf2f(v1[6]), bf2f(v1[7]));
      } else {
        bf16* dst = (bf16*)aout + gi;
        *reinterpret_cast<uint4*>(dst + 0) = *reinterpret_cast<const uint4*>(&v0);
        *reinterpret_cast<uint4*>(dst + 8) = *reinterpret_cast<const uint4*>(&v1);
      }
    }
    __syncthreads();
  }

  // fully-masked region of causal heads: probs exactly 0 (coalesced)
  if (is_local) {
    const int pr = 16 * w + (ln >> 2);
    const size_t rbase = arow0 + (size_t)pr * L;
    for (int c = nkt * 64 + (ln & 3) * 16; c < L; c += 64) {
      if constexpr (IsF32<T>::value) {
        float* dst = (float*)aout + rbase + c;
        const float4 z4 = make_float4(0.f, 0.f, 0.f, 0.f);
        *reinterpret_cast<float4*>(dst + 0) = z4;
        *reinterpret_cast<float4*>(dst + 4) = z4;
        *reinterpret_cast<float4*>(dst + 8) = z4;
        *reinterpret_cast<float4*>(dst + 12) = z4;
      } else {
        bf16* dst = (bf16*)aout + rbase + c;
        const uint4 z4 = make_uint4(0u, 0u, 0u, 0u);
        *reinterpret_cast<uint4*>(dst + 0) = z4;
        *reinterpret_cast<uint4*>(dst + 8) = z4;
      }
    }
  }

  // AO [B,L,D] as bf16 hi plane (feeds 1-product out_proj)
  #pragma unroll
  for (int dt = 0; dt < 4; ++dt)
    #pragma unroll
    for (int r = 0; r < 4; ++r)
      AOh[((size_t)bb * L + q0 + 16 * w + 4 * hi + r) * D + h * HD + dt * 16 + m] =
          bfh(o_[dt][r]);
}

// ---------------- Kernel 3: output projection (1-product MFMA GEMM) ------------
template<typename T>
__global__ __launch_bounds__(256)
void out_proj_kernel(const int* __restrict__ flag,
                     const ushort_t* __restrict__ ah_,
                     const ushort_t* __restrict__ wh,
                     const T* __restrict__ bo, T* __restrict__ out) {
  if (*flag != IsF32<T>::value) return;
  const int bid = blockIdx.x;                      // 512 blocks
  const int xcd = bid & 7, slot = bid >> 3;        // 64 slots
  const int col0 = xcd * 128;
  const int lane = threadIdx.x & 63, w = threadIdx.x >> 6;
  const int t0 = slot * 64 + w * 16;
  const int m = lane & 15, hi = lane >> 4;

  f32x4 acc[8] = {};
  const size_t arow = (size_t)(t0 + m) * D + hi * 8;
  for (int kc = 0; kc < 32; ++kc) {
    const int ko = kc * 32;
    bf16x8 ah = *reinterpret_cast<const bf16x8*>(ah_ + arow + ko);
    #pragma unroll
    for (int nt = 0; nt < 8; ++nt) {
      const size_t bo_ = (size_t)(col0 + nt * 16 + m) * D + ko + hi * 8;
      bf16x8 bhf = *reinterpret_cast<const bf16x8*>(wh + bo_);
      acc[nt] = MFMA16(ah, bhf, acc[nt]);
    }
  }
  #pragma unroll
  for (int nt = 0; nt < 8; ++nt) {
    const int col = col0 + nt * 16 + m;
    const float bv_ = ldf(bo, (size_t)col);
    #pragma unroll
    for (int r = 0; r < 4; ++r) {
      const int tok = t0 + 4 * hi + r;
      stf(out, (size_t)tok * D + col, acc[nt][r] + bv_);
    }
  }
}

template<typename T>
static void launch_path(void* const* d_in, void* d_out, void* d_ws, hipStream_t stream) {
  const int want = IsF32<T>::value;
  const int* flag = (const int*)d_ws;
  ushort_t* Qh  = (ushort_t*)((char*)d_ws + 256);
  ushort_t* Ql  = Qh + 4194304;
  ushort_t* Kh  = Ql + 4194304;
  ushort_t* Kl  = Kh + 4194304;
  ushort_t* Vth = Kl + 4194304;
  ushort_t* AOh = Vth + 4194304;          // total ws use ≈ 50.6 MB
  ushort_t* Woth = Kh;                    // Kh region dead after attn

  const T* x  = (const T*)d_in[0];
  const T* Wq = (const T*)d_in[1];
  const T* bq = (const T*)d_in[2];
  const T* Wk = (const T*)d_in[3];
  const T* bk = (const T*)d_in[4];
  const T* Wv = (const T*)d_in[5];
  const T* bv = (const T*)d_in[6];
  const T* Wo = (const T*)d_in[7];
  const T* bo = (const T*)d_in[8];
  const T* ls = (const T*)d_in[9];
  const T* gs = (const T*)d_in[10];

  T* out0   = (T*)d_out;
  T* attn_l = out0 + (size_t)B * L * D;
  T* attn_g = attn_l + (size_t)B * LH * L * L;
  // scratch inside the not-yet-written attn_g output region
  ushort_t* xh  = (ushort_t*)attn_g;
  ushort_t* xl  = xh + 4194304;
  ushort_t* Wt3 = xh + 8388608;           // 3 mats x (h,l) planes

  constexpr int NSA = IsF32<T>::value ? 2 : 1;

  if constexpr (IsF32<T>::value)
    split_f32_kernel<<<1024, 256, 0, stream>>>(flag, want, (const float*)x, xh, xl, 1048576);
  transW_kernel<T><<<dim3(16, 16, 3), 256, 0, stream>>>(flag, Wq, Wk, Wv, Wt3, 2);
  const ushort_t* xA = IsF32<T>::value ? xh : (const ushort_t*)x;
  proj_kernel<T, NSA><<<1536, 256, 0, stream>>>(
      flag, xA, xl, Wt3, bq, bk, bv, Qh, Ql, Kh, Kl, Vth);
  attn_kernel<T><<<1024, 256, 0, stream>>>(
      flag, Qh, Ql, Kh, Kl, Vth, ls, gs, attn_l, attn_g, AOh);
  transW_kernel<T><<<dim3(16, 16, 1), 256, 0, stream>>>(flag, Wo, Wo, Wo, Woth, 0);
  out_proj_kernel<T><<<512, 256, 0, stream>>>(flag, AOh, Woth, bo, out0);
}

extern "C" void kernel_launch(void* const* d_in, const int* in_sizes, int n_in,
                              void* d_out, int out_size, void* d_ws, size_t ws_size,
                              hipStream_t stream) {
  int* flag = (int*)d_ws;
  detect_dtype_kernel<<<1, 64, 0, stream>>>((const unsigned short*)d_in[0], flag);
  launch_path<float>(d_in, d_out, d_ws, stream);
  launch_path<bf16>(d_in, d_out, d_ws, stream);
}